// Round 2
// baseline (299.706 us; speedup 1.0000x reference)
//
#include <hip/hip_runtime.h>
#include <hip/hip_bf16.h>

#define EMB 10
#define DIN 36    // 2*EMB + 16 numeric
#define HID 128
#define BM  128   // rows per block

typedef __attribute__((ext_vector_type(8))) short short8;   // bf16x8 MFMA frag
typedef __attribute__((ext_vector_type(4))) float f32x4;    // fp32x4 acc frag

__device__ __forceinline__ short bf16_hi(float v) {
  __hip_bfloat16 h = __float2bfloat16(v);
  return *reinterpret_cast<short*>(&h);
}
__device__ __forceinline__ float bf16_to_f(short s) {
  __hip_bfloat16 h = *reinterpret_cast<__hip_bfloat16*>(&s);
  return __bfloat162float(h);
}

// Pack W1 (36x128) + b1 (as k=36 row, bias trick) into hi/lo bf16 B-fragments,
// K padded to 64. Layout: [term(2)][ct(8)][ks(2)][lane(64)][e(8)] bf16.
// B frag mapping (mfma_f32_16x16x32_bf16): col = ct*16+(lane&15),
// k = ks*32 + (lane>>4)*8 + e.
__global__ void prep_kernel(const float* __restrict__ W1, const float* __restrict__ b1,
                            short* __restrict__ Bpack) {
  int b = blockIdx.x;          // 32 blocks
  int term = b >> 4;           // 0 = hi, 1 = lo
  int ct   = (b >> 1) & 7;
  int ks   = b & 1;
  int l = threadIdx.x;         // 0..63
  int col = ct * 16 + (l & 15);
  int kb  = ks * 32 + (l >> 4) * 8;
  short8 o;
#pragma unroll
  for (int e = 0; e < 8; ++e) {
    int k = kb + e;
    float v = 0.0f;
    if (k < DIN)       v = W1[k * HID + col];
    else if (k == DIN) v = b1[col];
    short hb = bf16_hi(v);
    o[e] = (term == 0) ? hb : bf16_hi(v - bf16_to_f(hb));
  }
  *(short8*)(Bpack + (size_t)(((term * 8 + ct) * 2 + ks) * 64 + l) * 8) = o;
}

__global__ __launch_bounds__(256, 5)
void fused_kernel(const int* __restrict__ t1, const int* __restrict__ t2,
                  const float* __restrict__ numf,
                  const float* __restrict__ tab1, const float* __restrict__ tab2,
                  const short* __restrict__ Bpack,
                  const float* __restrict__ W2, const float* __restrict__ b2,
                  float* __restrict__ out, int N) {
  __shared__ float E1[BM + 2][11];   // halo rows, stride 11 (odd -> 2-way free)
  __shared__ float E2[BM + 6][11];
  __shared__ float Cs[BM][38];       // fp32 combined rows; [37] = 0 pad
  __shared__ float W2s[HID];

  const int tid = threadIdx.x;
  const long base = (long)blockIdx.x * BM;
  const long row = base + tid;                       // valid when tid < BM
  const bool rv = (tid < BM) && (row < (long)N);

  // prefetch this row's numeric features
  float4 nf0, nf1, nf2, nf3;
  if (rv) {
    const float4* np = (const float4*)(numf + row * 16);
    nf0 = np[0]; nf1 = np[1]; nf2 = np[2]; nf3 = np[3];
  }
  // E1 halo gather: threads 0..129 (table rows are 40 B, 8 B-aligned -> float2)
  if (tid < BM + 2) {
    long g = base - 1 + tid;
    if (g >= 0 && g < N) {
      const float2* src = (const float2*)(tab1 + (long)t1[g] * EMB);
#pragma unroll
      for (int i = 0; i < 5; ++i) {
        float2 v = src[i];
        E1[tid][2 * i] = v.x; E1[tid][2 * i + 1] = v.y;
      }
    }
  }
  // E2 halo gather: threads 122..255
  {
    int h = tid - (256 - (BM + 6));
    if (h >= 0) {
      long g = base - 3 + h;
      if (g >= 0 && g < N) {
        const float2* src = (const float2*)(tab2 + (long)t2[g] * EMB);
#pragma unroll
        for (int i = 0; i < 5; ++i) {
          float2 v = src[i];
          E2[h][2 * i] = v.x; E2[h][2 * i + 1] = v.y;
        }
      }
    }
  }
  if (tid >= 128) W2s[tid - 128] = W2[tid - 128];
  __syncthreads();

  // Build combined[36] + bias slot in fp32, store row to LDS
  if (rv) {
    float c[DIN + 1];
    {
      float s[EMB] = {0,0,0,0,0,0,0,0,0,0};
      int cnt = 0;
#pragma unroll
      for (int d = 0; d < 3; ++d) {
        long g = row - 1 + d;
        if (g >= 0 && g < N) {
          int h = tid + d;
#pragma unroll
          for (int i = 0; i < EMB; ++i) s[i] += E1[h][i];
          ++cnt;
        }
      }
      float inv = 1.0f / (float)cnt;
#pragma unroll
      for (int i = 0; i < EMB; ++i) c[i] = s[i] * inv;
    }
    {
      float s[EMB] = {0,0,0,0,0,0,0,0,0,0};
      int cnt = 0;
#pragma unroll
      for (int d = 0; d < 7; ++d) {
        long g = row - 3 + d;
        if (g >= 0 && g < N) {
          int h = tid + d;
#pragma unroll
          for (int i = 0; i < EMB; ++i) s[i] += E2[h][i];
          ++cnt;
        }
      }
      float inv = 1.0f / (float)cnt;
#pragma unroll
      for (int i = 0; i < EMB; ++i) c[EMB + i] = s[i] * inv;
    }
    c[20] = nf0.x; c[21] = nf0.y; c[22] = nf0.z; c[23] = nf0.w;
    c[24] = nf1.x; c[25] = nf1.y; c[26] = nf1.z; c[27] = nf1.w;
    c[28] = nf2.x; c[29] = nf2.y; c[30] = nf2.z; c[31] = nf2.w;
    c[32] = nf3.x; c[33] = nf3.y; c[34] = nf3.z; c[35] = nf3.w;
    c[DIN] = 1.0f;   // bias slot multiplies packed b1 row

#pragma unroll
    for (int k = 0; k <= DIN; ++k) Cs[tid][k] = c[k];
    Cs[tid][37] = 0.0f;
  }
  __syncthreads();

  // MFMA phase: 4 waves x 2 row-tiles each.
  // A frag (16x16x32): row = lane&15, k = ks*32 + (lane>>4)*8 + e.
  const int wid = tid >> 6;
  const int l = tid & 63;
  const int arow = l & 15;
  const int kg = l >> 4;

  short8 aHi[2][2], aLo[2][2];  // [rtl][ks]
#pragma unroll
  for (int rtl = 0; rtl < 2; ++rtl) {
    const int r = (wid * 2 + rtl) * 16 + arow;
    const float* crow = &Cs[r][0];
    {
      float v[8];
#pragma unroll
      for (int i = 0; i < 4; ++i) {
        float2 t = *(const float2*)(crow + kg * 8 + 2 * i);
        v[2 * i] = t.x; v[2 * i + 1] = t.y;
      }
#pragma unroll
      for (int e = 0; e < 8; ++e) {
        short hb = bf16_hi(v[e]);
        aHi[rtl][0][e] = hb;
        aLo[rtl][0][e] = bf16_hi(v[e] - bf16_to_f(hb));
      }
    }
    if (kg == 0) {   // ks=1 only lanes 0..15 carry data (k = 32..36)
      float v[8];
#pragma unroll
      for (int i = 0; i < 3; ++i) {
        float2 t = *(const float2*)(crow + 32 + 2 * i);
        v[2 * i] = t.x; v[2 * i + 1] = t.y;
      }
      v[6] = 0.0f; v[7] = 0.0f;
#pragma unroll
      for (int e = 0; e < 8; ++e) {
        short hb = bf16_hi(v[e]);
        aHi[rtl][1][e] = hb;
        aLo[rtl][1][e] = bf16_hi(v[e] - bf16_to_f(hb));
      }
    } else {
#pragma unroll
      for (int e = 0; e < 8; ++e) { aHi[rtl][1][e] = 0; aLo[rtl][1][e] = 0; }
    }
  }

  float part[2][4] = {{0,0,0,0},{0,0,0,0}};
#pragma unroll
  for (int ct = 0; ct < 8; ++ct) {
    short8 bb[2][2];
#pragma unroll
    for (int term = 0; term < 2; ++term)
#pragma unroll
      for (int ks = 0; ks < 2; ++ks)
        bb[term][ks] = *(const short8*)(Bpack +
            (size_t)(((term * 8 + ct) * 2 + ks) * 64 + l) * 8);
    float w2c = W2s[ct * 16 + (l & 15)];
#pragma unroll
    for (int rtl = 0; rtl < 2; ++rtl) {
      f32x4 acc = {0.0f, 0.0f, 0.0f, 0.0f};
#pragma unroll
      for (int ks = 0; ks < 2; ++ks) {
        acc = __builtin_amdgcn_mfma_f32_16x16x32_bf16(aHi[rtl][ks], bb[0][ks], acc, 0, 0, 0);
        acc = __builtin_amdgcn_mfma_f32_16x16x32_bf16(aLo[rtl][ks], bb[0][ks], acc, 0, 0, 0);
        acc = __builtin_amdgcn_mfma_f32_16x16x32_bf16(aHi[rtl][ks], bb[1][ks], acc, 0, 0, 0);
      }
#pragma unroll
      for (int r = 0; r < 4; ++r) {
        float hv = fmaxf(acc[r], 0.0f);    // relu(h + b1) — b1 folded via bias slot
        part[rtl][r] += hv * w2c;          // partial W2 dot
      }
    }
  }
  // reduce the W2 dot across the 16 column-lanes
#pragma unroll
  for (int off = 1; off < 16; off <<= 1) {
#pragma unroll
    for (int rtl = 0; rtl < 2; ++rtl)
#pragma unroll
      for (int r = 0; r < 4; ++r)
        part[rtl][r] += __shfl_xor(part[rtl][r], off, 64);
  }
  if ((l & 15) < 4) {
    float b2v = b2[0];
#pragma unroll
    for (int rtl = 0; rtl < 2; ++rtl) {
      int rt = wid * 2 + rtl;
      long grow = base + rt * 16 + (l >> 4) * 4 + (l & 15);
      if (grow < N) {
        float x = part[rtl][l & 15] + b2v;
        out[grow] = 1.0f / (1.0f + expf(-x));
      }
    }
  }
}

extern "C" void kernel_launch(void* const* d_in, const int* in_sizes, int n_in,
                              void* d_out, int out_size, void* d_ws, size_t ws_size,
                              hipStream_t stream) {
  const int*   t1   = (const int*)d_in[0];
  const int*   t2   = (const int*)d_in[1];
  const float* numf = (const float*)d_in[2];
  const float* tab1 = (const float*)d_in[3];
  const float* tab2 = (const float*)d_in[4];
  const float* W1   = (const float*)d_in[5];
  const float* b1   = (const float*)d_in[6];
  const float* W2   = (const float*)d_in[7];
  const float* b2   = (const float*)d_in[8];
  float* out = (float*)d_out;
  const int N = in_sizes[0];
  short* Bpack = (short*)d_ws;   // 32 KB

  hipLaunchKernelGGL(prep_kernel, dim3(32), dim3(64), 0, stream, W1, b1, Bpack);
  int nblk = (N + BM - 1) / BM;
  hipLaunchKernelGGL(fused_kernel, dim3(nblk), dim3(256), 0, stream,
                     t1, t2, numf, tab1, tab2, Bpack, W2, b2, out, N);
}

// Round 3
// 202.175 us; speedup vs baseline: 1.4824x; 1.4824x over previous
//
#include <hip/hip_runtime.h>
#include <hip/hip_bf16.h>

#define EMB 10
#define DIN 36    // 2*EMB + 16 numeric
#define HID 128
#define BM  128   // rows per block

typedef __attribute__((ext_vector_type(8))) short short8;   // bf16x8 MFMA frag
typedef __attribute__((ext_vector_type(4))) float f32x4;    // fp32x4 acc frag

__device__ __forceinline__ short bf16_hi(float v) {
  __hip_bfloat16 h = __float2bfloat16(v);
  return *reinterpret_cast<short*>(&h);
}
__device__ __forceinline__ float bf16_to_f(short s) {
  __hip_bfloat16 h = *reinterpret_cast<__hip_bfloat16*>(&s);
  return __bfloat162float(h);
}

// Pack W1 (36x128) + b1 (as k=36 row, bias trick) into hi/lo bf16 B-fragments,
// K padded to 64. Layout: [term(2)][ct(8)][ks(2)][lane(64)][e(8)] bf16.
// B frag mapping (mfma_f32_16x16x32_bf16): col = ct*16+(lane&15),
// k = ks*32 + (lane>>4)*8 + e.
__global__ void prep_kernel(const float* __restrict__ W1, const float* __restrict__ b1,
                            short* __restrict__ Bpack) {
  int b = blockIdx.x;          // 32 blocks
  int term = b >> 4;           // 0 = hi, 1 = lo
  int ct   = (b >> 1) & 7;
  int ks   = b & 1;
  int l = threadIdx.x;         // 0..63
  int col = ct * 16 + (l & 15);
  int kb  = ks * 32 + (l >> 4) * 8;
  short8 o;
#pragma unroll
  for (int e = 0; e < 8; ++e) {
    int k = kb + e;
    float v = 0.0f;
    if (k < DIN)       v = W1[k * HID + col];
    else if (k == DIN) v = b1[col];
    short hb = bf16_hi(v);
    o[e] = (term == 0) ? hb : bf16_hi(v - bf16_to_f(hb));
  }
  *(short8*)(Bpack + (size_t)(((term * 8 + ct) * 2 + ks) * 64 + l) * 8) = o;
}

// launch_bounds(256,4): VGPR cap 128 >> natural usage -> NO spill.
// (256,5) capped at 96 and spilled ~400 B/row of scratch (R2 regression).
__global__ __launch_bounds__(256, 4)
void fused_kernel(const int* __restrict__ t1, const int* __restrict__ t2,
                  const float* __restrict__ numf,
                  const float* __restrict__ tab1, const float* __restrict__ tab2,
                  const short* __restrict__ Bpack,
                  const float* __restrict__ W2, const float* __restrict__ b2,
                  float* __restrict__ out, int N) {
  __shared__ float E1[BM + 2][11];   // halo rows, stride 11 (odd -> 2-way free)
  __shared__ float E2[BM + 6][11];
  __shared__ float Cs[BM][38];       // fp32 combined rows; [37] = 0 pad
  __shared__ float W2s[HID];

  const int tid = threadIdx.x;
  const long base = (long)blockIdx.x * BM;
  const long row = base + tid;                       // valid when tid < BM
  const bool rv = (tid < BM) && (row < (long)N);

  // prefetch this row's numeric features
  float4 nf0, nf1, nf2, nf3;
  if (rv) {
    const float4* np = (const float4*)(numf + row * 16);
    nf0 = np[0]; nf1 = np[1]; nf2 = np[2]; nf3 = np[3];
  }
  // E1 halo gather: threads 0..129 (table rows are 40 B, 8 B-aligned -> float2)
  if (tid < BM + 2) {
    long g = base - 1 + tid;
    if (g >= 0 && g < N) {
      const float2* src = (const float2*)(tab1 + (long)t1[g] * EMB);
#pragma unroll
      for (int i = 0; i < 5; ++i) {
        float2 v = src[i];
        E1[tid][2 * i] = v.x; E1[tid][2 * i + 1] = v.y;
      }
    }
  }
  // E2 halo gather: threads 122..255
  {
    int h = tid - (256 - (BM + 6));
    if (h >= 0) {
      long g = base - 3 + h;
      if (g >= 0 && g < N) {
        const float2* src = (const float2*)(tab2 + (long)t2[g] * EMB);
#pragma unroll
        for (int i = 0; i < 5; ++i) {
          float2 v = src[i];
          E2[h][2 * i] = v.x; E2[h][2 * i + 1] = v.y;
        }
      }
    }
  }
  if (tid >= 128) W2s[tid - 128] = W2[tid - 128];
  __syncthreads();

  // Build combined[36] + bias slot in fp32, store row to LDS
  if (rv) {
    float c[DIN + 1];
    {
      float s[EMB] = {0,0,0,0,0,0,0,0,0,0};
      int cnt = 0;
#pragma unroll
      for (int d = 0; d < 3; ++d) {
        long g = row - 1 + d;
        if (g >= 0 && g < N) {
          int h = tid + d;
#pragma unroll
          for (int i = 0; i < EMB; ++i) s[i] += E1[h][i];
          ++cnt;
        }
      }
      float inv = 1.0f / (float)cnt;
#pragma unroll
      for (int i = 0; i < EMB; ++i) c[i] = s[i] * inv;
    }
    {
      float s[EMB] = {0,0,0,0,0,0,0,0,0,0};
      int cnt = 0;
#pragma unroll
      for (int d = 0; d < 7; ++d) {
        long g = row - 3 + d;
        if (g >= 0 && g < N) {
          int h = tid + d;
#pragma unroll
          for (int i = 0; i < EMB; ++i) s[i] += E2[h][i];
          ++cnt;
        }
      }
      float inv = 1.0f / (float)cnt;
#pragma unroll
      for (int i = 0; i < EMB; ++i) c[EMB + i] = s[i] * inv;
    }
    c[20] = nf0.x; c[21] = nf0.y; c[22] = nf0.z; c[23] = nf0.w;
    c[24] = nf1.x; c[25] = nf1.y; c[26] = nf1.z; c[27] = nf1.w;
    c[28] = nf2.x; c[29] = nf2.y; c[30] = nf2.z; c[31] = nf2.w;
    c[32] = nf3.x; c[33] = nf3.y; c[34] = nf3.z; c[35] = nf3.w;
    c[DIN] = 1.0f;   // bias slot multiplies packed b1 row

#pragma unroll
    for (int k = 0; k <= DIN; ++k) Cs[tid][k] = c[k];
    Cs[tid][37] = 0.0f;
  }
  __syncthreads();

  // MFMA phase: 4 waves x 2 row-tiles each.
  // A frag (16x16x32): row = lane&15, k = ks*32 + (lane>>4)*8 + e.
  const int wid = tid >> 6;
  const int l = tid & 63;
  const int arow = l & 15;
  const int kg = l >> 4;

  short8 aHi[2][2], aLo[2][2];  // [rtl][ks]
#pragma unroll
  for (int rtl = 0; rtl < 2; ++rtl) {
    const int r = (wid * 2 + rtl) * 16 + arow;
    const float* crow = &Cs[r][0];
    {
      float v[8];
#pragma unroll
      for (int i = 0; i < 4; ++i) {
        float2 t = *(const float2*)(crow + kg * 8 + 2 * i);
        v[2 * i] = t.x; v[2 * i + 1] = t.y;
      }
#pragma unroll
      for (int e = 0; e < 8; ++e) {
        short hb = bf16_hi(v[e]);
        aHi[rtl][0][e] = hb;
        aLo[rtl][0][e] = bf16_hi(v[e] - bf16_to_f(hb));
      }
    }
    if (kg == 0) {   // ks=1 only lanes 0..15 carry data (k = 32..36)
      float v[8];
#pragma unroll
      for (int i = 0; i < 3; ++i) {
        float2 t = *(const float2*)(crow + 32 + 2 * i);
        v[2 * i] = t.x; v[2 * i + 1] = t.y;
      }
      v[6] = 0.0f; v[7] = 0.0f;
#pragma unroll
      for (int e = 0; e < 8; ++e) {
        short hb = bf16_hi(v[e]);
        aHi[rtl][1][e] = hb;
        aLo[rtl][1][e] = bf16_hi(v[e] - bf16_to_f(hb));
      }
    } else {
#pragma unroll
      for (int e = 0; e < 8; ++e) { aHi[rtl][1][e] = 0; aLo[rtl][1][e] = 0; }
    }
  }

  float part[2][4] = {{0,0,0,0},{0,0,0,0}};
#pragma unroll
  for (int ct = 0; ct < 8; ++ct) {
    short8 bb[2][2];
#pragma unroll
    for (int term = 0; term < 2; ++term)
#pragma unroll
      for (int ks = 0; ks < 2; ++ks)
        bb[term][ks] = *(const short8*)(Bpack +
            (size_t)(((term * 8 + ct) * 2 + ks) * 64 + l) * 8);
    float w2c = W2s[ct * 16 + (l & 15)];
#pragma unroll
    for (int rtl = 0; rtl < 2; ++rtl) {
      f32x4 acc = {0.0f, 0.0f, 0.0f, 0.0f};
#pragma unroll
      for (int ks = 0; ks < 2; ++ks) {
        acc = __builtin_amdgcn_mfma_f32_16x16x32_bf16(aHi[rtl][ks], bb[0][ks], acc, 0, 0, 0);
        acc = __builtin_amdgcn_mfma_f32_16x16x32_bf16(aLo[rtl][ks], bb[0][ks], acc, 0, 0, 0);
        acc = __builtin_amdgcn_mfma_f32_16x16x32_bf16(aHi[rtl][ks], bb[1][ks], acc, 0, 0, 0);
      }
#pragma unroll
      for (int r = 0; r < 4; ++r) {
        float hv = fmaxf(acc[r], 0.0f);    // relu(h + b1) — b1 folded via bias slot
        part[rtl][r] += hv * w2c;          // partial W2 dot
      }
    }
  }
  // reduce the W2 dot across the 16 column-lanes
#pragma unroll
  for (int off = 1; off < 16; off <<= 1) {
#pragma unroll
    for (int rtl = 0; rtl < 2; ++rtl)
#pragma unroll
      for (int r = 0; r < 4; ++r)
        part[rtl][r] += __shfl_xor(part[rtl][r], off, 64);
  }
  if ((l & 15) < 4) {
    float b2v = b2[0];
#pragma unroll
    for (int rtl = 0; rtl < 2; ++rtl) {
      int rt = wid * 2 + rtl;
      long grow = base + rt * 16 + (l >> 4) * 4 + (l & 15);
      if (grow < N) {
        float x = part[rtl][l & 15] + b2v;
        out[grow] = 1.0f / (1.0f + expf(-x));
      }
    }
  }
}

extern "C" void kernel_launch(void* const* d_in, const int* in_sizes, int n_in,
                              void* d_out, int out_size, void* d_ws, size_t ws_size,
                              hipStream_t stream) {
  const int*   t1   = (const int*)d_in[0];
  const int*   t2   = (const int*)d_in[1];
  const float* numf = (const float*)d_in[2];
  const float* tab1 = (const float*)d_in[3];
  const float* tab2 = (const float*)d_in[4];
  const float* W1   = (const float*)d_in[5];
  const float* b1   = (const float*)d_in[6];
  const float* W2   = (const float*)d_in[7];
  const float* b2   = (const float*)d_in[8];
  float* out = (float*)d_out;
  const int N = in_sizes[0];
  short* Bpack = (short*)d_ws;   // 32 KB

  hipLaunchKernelGGL(prep_kernel, dim3(32), dim3(64), 0, stream, W1, b1, Bpack);
  int nblk = (N + BM - 1) / BM;
  hipLaunchKernelGGL(fused_kernel, dim3(nblk), dim3(256), 0, stream,
                     t1, t2, numf, tab1, tab2, Bpack, W2, b2, out, N);
}

// Round 5
// 182.110 us; speedup vs baseline: 1.6457x; 1.1102x over previous
//
#include <hip/hip_runtime.h>
#include <hip/hip_bf16.h>

#define EMB 10
#define DIN 36    // 2*EMB + 16 numeric
#define HID 128
#define BM  128   // rows per block

typedef __attribute__((ext_vector_type(8))) short short8;   // bf16x8 MFMA frag
typedef __attribute__((ext_vector_type(4))) float f32x4;    // fp32x4 acc frag

__device__ __forceinline__ short bf16_hi(float v) {
  __hip_bfloat16 h = __float2bfloat16(v);
  return *reinterpret_cast<short*>(&h);
}
__device__ __forceinline__ float bf16_to_f(short s) {
  __hip_bfloat16 h = *reinterpret_cast<__hip_bfloat16*>(&s);
  return __bfloat162float(h);
}

// Pack W1 (36x128) + b1 (as k=36 row, bias trick) into hi/lo bf16 B-fragments,
// K padded to 64. Layout: [term(2)][ct(8)][ks(2)][lane(64)][e(8)] bf16.
__global__ void prep_kernel(const float* __restrict__ W1, const float* __restrict__ b1,
                            short* __restrict__ Bpack) {
  int b = blockIdx.x;          // 32 blocks
  int term = b >> 4;           // 0 = hi, 1 = lo
  int ct   = (b >> 1) & 7;
  int ks   = b & 1;
  int l = threadIdx.x;         // 0..63
  int col = ct * 16 + (l & 15);
  int kb  = ks * 32 + (l >> 4) * 8;
  short8 o;
#pragma unroll
  for (int e = 0; e < 8; ++e) {
    int k = kb + e;
    float v = 0.0f;
    if (k < DIN)       v = W1[k * HID + col];
    else if (k == DIN) v = b1[col];
    short hb = bf16_hi(v);
    o[e] = (term == 0) ? hb : bf16_hi(v - bf16_to_f(hb));
  }
  *(short8*)(Bpack + (size_t)(((term * 8 + ct) * 2 + ks) * 64 + l) * 8) = o;
}

// no min-waves clause: avoid register caps (R2 spill lesson); LDS (31.6KB)
// limits naturally at 5 blocks/CU.
__global__ __launch_bounds__(256)
void fused_kernel(const int* __restrict__ t1, const int* __restrict__ t2,
                  const float* __restrict__ numf,
                  const float* __restrict__ tab1, const float* __restrict__ tab2,
                  const short* __restrict__ Bpack,
                  const float* __restrict__ W2, const float* __restrict__ b2,
                  float* __restrict__ out, int N) {
  __shared__ float E1[BM + 2][11];   // halo rows, stride 11 (odd -> conflict-benign)
  __shared__ float E2[BM + 6][11];
  __shared__ float Cs[BM][38];       // fp32 combined rows; [36]=1 bias, [37]=0 pad
  __shared__ float W2s[HID];

  const int tid = threadIdx.x;
  const long base = (long)blockIdx.x * BM;
  const int rloc = tid & 127;        // numeric row this thread serves
  const int half = tid >> 7;         // which 8 of 16 numeric dims
  const long rowm = base + rloc;

  // numeric prefetch (independent of everything; latency hides under gathers)
  float4 nfa, nfb;
  if (rowm < (long)N) {
    const float4* np = (const float4*)(numf + rowm * 16 + half * 8);
    nfa = np[0]; nfb = np[1];
  }

  // E1 halo gather: threads 0..129; invalid rows ZERO-FILLED (sliding tasks
  // read fixed windows; edge counts handled via inv()).
  if (tid < BM + 2) {
    long g = base - 1 + tid;
    if (g >= 0 && g < (long)N) {
      const float2* src = (const float2*)(tab1 + (long)t1[g] * EMB);
#pragma unroll
      for (int i = 0; i < 5; ++i) {
        float2 v = src[i];
        E1[tid][2 * i] = v.x; E1[tid][2 * i + 1] = v.y;
      }
    } else {
#pragma unroll
      for (int i = 0; i < EMB; ++i) E1[tid][i] = 0.0f;
    }
  }
  // E2 halo gather: threads 122..255
  {
    int h = tid - (256 - (BM + 6));
    if (h >= 0) {
      long g = base - 3 + h;
      if (g >= 0 && g < (long)N) {
        const float2* src = (const float2*)(tab2 + (long)t2[g] * EMB);
#pragma unroll
        for (int i = 0; i < 5; ++i) {
          float2 v = src[i];
          E2[h][2 * i] = v.x; E2[h][2 * i + 1] = v.y;
        }
      } else {
#pragma unroll
        for (int i = 0; i < EMB; ++i) E2[h][i] = 0.0f;
      }
    }
  }
  if (tid < HID) W2s[tid] = W2[tid];
  __syncthreads();

  // ---- build phase: sliding-window tasks, (dim, row-group) per thread ----
  if (tid < 120) {
    // E1 window-3 means: 12 groups x 11 rows x 10 dims
    int grp = tid / 10, d = tid - grp * 10;
    int r0 = grp * 11;
    float e[13];
#pragma unroll
    for (int i = 0; i < 13; ++i) {
      int h = r0 + i; if (h > 129) h = 129;
      e[i] = E1[h][d];
    }
#pragma unroll
    for (int i = 0; i < 11; ++i) {
      int rr = r0 + i;
      if (rr < BM) {
        long row = base + rr;
        float inv = 1.0f / 3.0f;
        if (row == 0 || row >= (long)N - 1) {   // rare: array edges only
          long lo = row - 1; if (lo < 0) lo = 0;
          long hi = row + 2; if (hi > (long)N) hi = (long)N;
          long c = hi - lo;  if (c < 1) c = 1;
          inv = 1.0f / (float)c;
        }
        Cs[rr][d] = (e[i] + e[i + 1] + e[i + 2]) * inv;
      }
    }
  } else if (tid < 250) {
    // E2 window-7 means: 13 groups x 10 rows x 10 dims
    int u = tid - 120;
    int grp = u / 10, d = u - grp * 10;
    int r0 = grp * 10;
    float e[16];
#pragma unroll
    for (int i = 0; i < 16; ++i) {
      int h = r0 + i; if (h > 133) h = 133;
      e[i] = E2[h][d];
    }
    float w = e[0] + e[1] + e[2] + e[3] + e[4] + e[5] + e[6];
#pragma unroll
    for (int i = 0; i < 10; ++i) {
      int rr = r0 + i;
      if (rr < BM) {
        long row = base + rr;
        float inv = 1.0f / 7.0f;
        if (row < 3 || row >= (long)N - 3) {    // rare: array edges only
          long lo = row - 3; if (lo < 0) lo = 0;
          long hi = row + 4; if (hi > (long)N) hi = (long)N;
          long c = hi - lo;  if (c < 1) c = 1;
          inv = 1.0f / (float)c;
        }
        Cs[rr][10 + d] = w * inv;
      }
      if (i < 9) w += e[i + 7] - e[i];
    }
  }
  // numeric features + bias slots straight into Cs
  if (rowm < (long)N) {
    float* cp = &Cs[rloc][20 + half * 8];
    *(float2*)(cp + 0) = make_float2(nfa.x, nfa.y);
    *(float2*)(cp + 2) = make_float2(nfa.z, nfa.w);
    *(float2*)(cp + 4) = make_float2(nfb.x, nfb.y);
    *(float2*)(cp + 6) = make_float2(nfb.z, nfb.w);
    if (half == 0) *(float2*)(&Cs[rloc][36]) = make_float2(1.0f, 0.0f);
  }
  __syncthreads();

  // ---- MFMA phase: 4 waves x 2 row-tiles each ----
  // A frag (16x16x32): row = lane&15, k = ks*32 + (lane>>4)*8 + e.
  const int wid = tid >> 6;
  const int l = tid & 63;
  const int arow = l & 15;
  const int kg = l >> 4;

  short8 aHi[2][2], aLo[2][2];  // [rtl][ks]
#pragma unroll
  for (int rtl = 0; rtl < 2; ++rtl) {
    const int r = (wid * 2 + rtl) * 16 + arow;
    const float* crow = &Cs[r][0];
    {
      float v[8];
#pragma unroll
      for (int i = 0; i < 4; ++i) {
        float2 t = *(const float2*)(crow + kg * 8 + 2 * i);
        v[2 * i] = t.x; v[2 * i + 1] = t.y;
      }
#pragma unroll
      for (int e = 0; e < 8; ++e) {
        short hb = bf16_hi(v[e]);
        aHi[rtl][0][e] = hb;
        aLo[rtl][0][e] = bf16_hi(v[e] - bf16_to_f(hb));
      }
    }
    if (kg == 0) {   // ks=1: only k = 32..37 carry data
      float v[8];
#pragma unroll
      for (int i = 0; i < 3; ++i) {
        float2 t = *(const float2*)(crow + 32 + 2 * i);
        v[2 * i] = t.x; v[2 * i + 1] = t.y;
      }
      v[6] = 0.0f; v[7] = 0.0f;
#pragma unroll
      for (int e = 0; e < 8; ++e) {
        short hb = bf16_hi(v[e]);
        aHi[rtl][1][e] = hb;
        aLo[rtl][1][e] = bf16_hi(v[e] - bf16_to_f(hb));
      }
    } else {
#pragma unroll
      for (int e = 0; e < 8; ++e) { aHi[rtl][1][e] = 0; aLo[rtl][1][e] = 0; }
    }
  }

  float part[2][4] = {{0,0,0,0},{0,0,0,0}};
#pragma unroll
  for (int ct = 0; ct < 8; ++ct) {
    short8 bb[2][2];
#pragma unroll
    for (int term = 0; term < 2; ++term)
#pragma unroll
      for (int ks = 0; ks < 2; ++ks)
        bb[term][ks] = *(const short8*)(Bpack +
            (size_t)(((term * 8 + ct) * 2 + ks) * 64 + l) * 8);
    float w2c = W2s[ct * 16 + (l & 15)];
#pragma unroll
    for (int rtl = 0; rtl < 2; ++rtl) {
      f32x4 acc = {0.0f, 0.0f, 0.0f, 0.0f};
#pragma unroll
      for (int ks = 0; ks < 2; ++ks) {
        acc = __builtin_amdgcn_mfma_f32_16x16x32_bf16(aHi[rtl][ks], bb[0][ks], acc, 0, 0, 0);
        acc = __builtin_amdgcn_mfma_f32_16x16x32_bf16(aLo[rtl][ks], bb[0][ks], acc, 0, 0, 0);
        acc = __builtin_amdgcn_mfma_f32_16x16x32_bf16(aHi[rtl][ks], bb[1][ks], acc, 0, 0, 0);
      }
#pragma unroll
      for (int r = 0; r < 4; ++r) {
        float hv = fmaxf(acc[r], 0.0f);    // relu(h + b1) — b1 folded via bias slot
        part[rtl][r] += hv * w2c;          // partial W2 dot
      }
    }
  }
  // reduce the W2 dot across the 16 column-lanes
#pragma unroll
  for (int off = 1; off < 16; off <<= 1) {
#pragma unroll
    for (int rtl = 0; rtl < 2; ++rtl)
#pragma unroll
      for (int r = 0; r < 4; ++r)
        part[rtl][r] += __shfl_xor(part[rtl][r], off, 64);
  }
  if ((l & 15) < 4) {
    float b2v = b2[0];
#pragma unroll
    for (int rtl = 0; rtl < 2; ++rtl) {
      int rt = wid * 2 + rtl;
      long grow = base + rt * 16 + (l >> 4) * 4 + (l & 15);
      if (grow < (long)N) {
        float x = part[rtl][l & 15] + b2v;
        out[grow] = 1.0f / (1.0f + expf(-x));
      }
    }
  }
}

extern "C" void kernel_launch(void* const* d_in, const int* in_sizes, int n_in,
                              void* d_out, int out_size, void* d_ws, size_t ws_size,
                              hipStream_t stream) {
  const int*   t1   = (const int*)d_in[0];
  const int*   t2   = (const int*)d_in[1];
  const float* numf = (const float*)d_in[2];
  const float* tab1 = (const float*)d_in[3];
  const float* tab2 = (const float*)d_in[4];
  const float* W1   = (const float*)d_in[5];
  const float* b1   = (const float*)d_in[6];
  const float* W2   = (const float*)d_in[7];
  const float* b2   = (const float*)d_in[8];
  float* out = (float*)d_out;
  const int N = in_sizes[0];
  short* Bpack = (short*)d_ws;   // 64 KB

  hipLaunchKernelGGL(prep_kernel, dim3(32), dim3(64), 0, stream, W1, b1, Bpack);
  int nblk = (N + BM - 1) / BM;
  hipLaunchKernelGGL(fused_kernel, dim3(nblk), dim3(256), 0, stream,
                     t1, t2, numf, tab1, tab2, Bpack, W2, b2, out, N);
}